// Round 7
// baseline (968.951 us; speedup 1.0000x reference)
//
#include <hip/hip_runtime.h>
#include <cfloat>

#define NEG_SLOPE 0.2f

// ---------------- CSR build ----------------
__global__ __launch_bounds__(256) void zero_kernel(int* __restrict__ counts,
                                                   int* __restrict__ cursor, int n) {
    int gid = blockIdx.x * 256 + threadIdx.x;
    if (gid < n) { counts[gid] = 0; cursor[gid] = 0; }
}

__global__ __launch_bounds__(256) void count_kernel(const int* __restrict__ dst,
                                                    int* __restrict__ counts, int E) {
    int e = blockIdx.x * 256 + threadIdx.x;
    if (e < E) atomicAdd(&counts[dst[e]], 1);
}

// single-block exclusive scan: offs[0..N], offs[i] = sum counts[0..i)
__global__ __launch_bounds__(256) void scan_kernel(const int* __restrict__ counts,
                                                   int* __restrict__ offs, int N) {
    __shared__ int wtot[4];
    __shared__ int wexc[4];
    __shared__ int chtot;
    __shared__ int carry_s;
    int t = threadIdx.x, lane = t & 63, w = t >> 6;
    if (t == 0) { offs[0] = 0; carry_s = 0; }
    __syncthreads();
    for (int base = 0; base < N; base += 256) {
        int v = (base + t < N) ? counts[base + t] : 0;
        // inclusive wave scan
        int x = v;
        #pragma unroll
        for (int d = 1; d < 64; d <<= 1) {
            int y = __shfl_up(x, d);
            if (lane >= d) x += y;
        }
        if (lane == 63) wtot[w] = x;
        __syncthreads();
        if (t == 0) {
            int s = 0;
            #pragma unroll
            for (int i = 0; i < 4; ++i) { wexc[i] = s; s += wtot[i]; }
            chtot = s;
        }
        __syncthreads();
        int incl = x + wexc[w];
        if (base + t < N) offs[base + t + 1] = carry_s + incl;
        __syncthreads();
        if (t == 0) carry_s += chtot;
        __syncthreads();
    }
}

__global__ __launch_bounds__(256) void scatter_kernel(
    const int* __restrict__ src, const int* __restrict__ dst,
    const int* __restrict__ offs, int* __restrict__ cursor,
    int* __restrict__ csr_src, int* __restrict__ csr_eid, int E) {
    int e = blockIdx.x * 256 + threadIdx.x;
    if (e >= E) return;
    int d = dst[e];
    int pos = offs[d] + atomicAdd(&cursor[d], 1);
    csr_src[pos] = src[e];
    csr_eid[pos] = e;
}

// ---------------- per-layer kernels ----------------
// xl = hin @ Wl + bl ; xr = hin @ Wr + br   (D=64)
__global__ __launch_bounds__(256) void node_gemm_kernel(
    const float* __restrict__ hin,
    const float* __restrict__ Wl, const float* __restrict__ bl,
    const float* __restrict__ Wr, const float* __restrict__ br,
    float* __restrict__ xl, float* __restrict__ xr, int nrows)
{
    __shared__ float sWl[4096];
    __shared__ float sWr[4096];
    int t = threadIdx.x;
    {
        float4* dl = (float4*)sWl; const float4* sl = (const float4*)Wl;
        float4* dr = (float4*)sWr; const float4* sr = (const float4*)Wr;
        for (int i = t; i < 1024; i += 256) { dl[i] = sl[i]; dr[i] = sr[i]; }
    }
    __syncthreads();
    int lane = t & 63;
    int row = blockIdx.x * 4 + (t >> 6);
    if (row >= nrows) return;
    float xv = hin[(size_t)row * 64 + lane];
    float accl = bl[lane];
    float accr = br[lane];
    #pragma unroll
    for (int k = 0; k < 64; ++k) {
        float xk = __shfl(xv, k);
        accl += xk * sWl[k * 64 + lane];
        accr += xk * sWr[k * 64 + lane];
    }
    xl[(size_t)row * 64 + lane] = accl;
    xr[(size_t)row * 64 + lane] = accr;
}

// one thread per (edge, head): score only (no atomics)
__global__ __launch_bounds__(256) void edge_score_kernel(
    const float* __restrict__ xl, const float* __restrict__ xr,
    const float* __restrict__ ea,
    const int* __restrict__ src, const int* __restrict__ dst,
    const float* __restrict__ We, const float* __restrict__ att,
    float* __restrict__ score, int E)
{
    __shared__ float sWe[1024];   // 16 x 64
    __shared__ float sAtt[64];    // 4 x 16
    int t = threadIdx.x;
    for (int i = t; i < 1024; i += 256) sWe[i] = We[i];
    if (t < 64) sAtt[t] = att[t];
    __syncthreads();
    int gid = blockIdx.x * 256 + t;
    int e = gid >> 2, h = gid & 3;
    if (e >= E) return;
    int s = src[e], d = dst[e];
    const float4* eap = (const float4*)(ea + (size_t)e * 16);
    float4 a0 = eap[0], a1 = eap[1], a2 = eap[2], a3 = eap[3];
    float av[16] = {a0.x, a0.y, a0.z, a0.w, a1.x, a1.y, a1.z, a1.w,
                    a2.x, a2.y, a2.z, a2.w, a3.x, a3.y, a3.z, a3.w};
    const float4* xls = (const float4*)(xl + (size_t)s * 64 + h * 16);
    const float4* xrd = (const float4*)(xr + (size_t)d * 64 + h * 16);
    float sc = 0.f;
    #pragma unroll
    for (int q = 0; q < 4; ++q) {
        float4 vl = xls[q];
        float4 vr = xrd[q];
        float lv[4] = {vl.x, vl.y, vl.z, vl.w};
        float rv[4] = {vr.x, vr.y, vr.z, vr.w};
        #pragma unroll
        for (int j = 0; j < 4; ++j) {
            int c = q * 4 + j;
            float ef = 0.f;
            #pragma unroll
            for (int k = 0; k < 16; ++k) ef += av[k] * sWe[k * 64 + h * 16 + c];
            float m = lv[j] + rv[j] + ef;
            m = (m >= 0.f) ? m : NEG_SLOPE * m;
            sc += m * sAtt[h * 16 + c];
        }
    }
    score[gid] = sc;
}

// one wave per node: max over in-edges, then double-accumulated softmax aggregate
__global__ __launch_bounds__(256) void node_pass_kernel(
    const float* __restrict__ score, const float* __restrict__ xl,
    const int* __restrict__ csr_src, const int* __restrict__ csr_eid,
    const int* __restrict__ offs, const float* __restrict__ bias,
    float* __restrict__ hout, int N)
{
    int t = threadIdx.x;
    int lane = t & 63;
    int node = blockIdx.x * 4 + (t >> 6);
    if (node >= N) return;
    int h = lane >> 4;
    int off = offs[node];
    int deg = offs[node + 1] - off;

    // pass 1: max score for this head (order-invariant)
    float mx = -FLT_MAX;
    for (int base = 0; base < deg; base += 64) {
        int lim = deg - base; if (lim > 64) lim = 64;
        int eidv = 0;
        if (lane < lim) eidv = csr_eid[off + base + lane];
        for (int j = 0; j < lim; ++j) {
            int e = __shfl(eidv, j);
            float sc = score[(size_t)e * 4 + h];
            mx = fmaxf(mx, sc);
        }
    }

    // pass 2: double accumulation (order jitter ~1e-16 only)
    double sSum = 0.0, O = 0.0;
    for (int base = 0; base < deg; base += 64) {
        int lim = deg - base; if (lim > 64) lim = 64;
        int eidv = 0, srcv = 0;
        if (lane < lim) {
            eidv = csr_eid[off + base + lane];
            srcv = csr_src[off + base + lane];
        }
        for (int j = 0; j < lim; ++j) {
            int e = __shfl(eidv, j);
            int s = __shfl(srcv, j);
            float sc = score[(size_t)e * 4 + h];
            float ex = expf(sc - mx);
            sSum += (double)ex;
            O += (double)ex * (double)xl[(size_t)s * 64 + lane];
        }
    }

    float v = (deg > 0) ? (float)(O / sSum) : 0.f;
    v += bias[lane];
    hout[(size_t)node * 64 + lane] = fmaxf(v, 0.f);
}

extern "C" void kernel_launch(void* const* d_in, const int* in_sizes, int n_in,
                              void* d_out, int out_size, void* d_ws, size_t ws_size,
                              hipStream_t stream) {
    const float* x    = (const float*)d_in[0];
    const int*   eidx = (const int*)d_in[1];
    const float* ea   = (const float*)d_in[2];
    const float* Wl   = (const float*)d_in[3];
    const float* bl   = (const float*)d_in[4];
    const float* Wr   = (const float*)d_in[5];
    const float* br   = (const float*)d_in[6];
    const float* We   = (const float*)d_in[7];
    const float* att  = (const float*)d_in[8];
    const float* bias = (const float*)d_in[9];
    float* out = (float*)d_out;

    const int N = in_sizes[0] / 64;
    const int E = in_sizes[1] / 2;
    const int* src = eidx;
    const int* dst = eidx + E;

    float* ws = (float*)d_ws;
    float* xl      = ws;                               // N*64
    float* xr      = xl + (size_t)N * 64;              // N*64
    float* score   = xr + (size_t)N * 64;              // E*4
    float* h_tmp   = score + (size_t)E * 4;            // N*64
    int* counts    = (int*)(h_tmp + (size_t)N * 64);   // N
    int* cursor    = counts + N;                       // N
    int* offs      = cursor + N;                       // N+1
    int* csr_src   = offs + N + 1;                     // E
    int* csr_eid   = csr_src + E;                      // E

    dim3 blk(256);
    int g_n   = (N + 255) / 256;
    int g_e   = (E + 255) / 256;
    int g_eh  = (E * 4 + 255) / 256;
    int g_gemm = (N + 3) / 4;
    int g_node = (N + 3) / 4;

    // CSR over dst (edge_index is layer-invariant)
    zero_kernel<<<g_n, blk, 0, stream>>>(counts, cursor, N);
    count_kernel<<<g_e, blk, 0, stream>>>(dst, counts, E);
    scan_kernel<<<1, blk, 0, stream>>>(counts, offs, N);
    scatter_kernel<<<g_e, blk, 0, stream>>>(src, dst, offs, cursor, csr_src, csr_eid, E);

    const float* hin = x;
    for (int l = 0; l < 3; ++l) {
        float* hout = (l == 2) ? out : h_tmp;
        node_gemm_kernel<<<g_gemm, blk, 0, stream>>>(hin, Wl + (size_t)l * 4096, bl + l * 64,
                                                     Wr + (size_t)l * 4096, br + l * 64, xl, xr, N);
        edge_score_kernel<<<g_eh, blk, 0, stream>>>(xl, xr, ea, src, dst,
                                                    We + (size_t)l * 1024, att + l * 64,
                                                    score, E);
        node_pass_kernel<<<g_node, blk, 0, stream>>>(score, xl, csr_src, csr_eid, offs,
                                                     bias + l * 64, hout, N);
        hin = hout;
    }
}

// Round 8
// 858.292 us; speedup vs baseline: 1.1289x; 1.1289x over previous
//
#include <hip/hip_runtime.h>
#include <cfloat>

#define NEG_SLOPE 0.2f

// ---------------- CSR build ----------------
__global__ __launch_bounds__(256) void zero_kernel(int* __restrict__ counts,
                                                   int* __restrict__ cursor, int n) {
    int gid = blockIdx.x * 256 + threadIdx.x;
    if (gid < n) { counts[gid] = 0; cursor[gid] = 0; }
}

__global__ __launch_bounds__(256) void count_kernel(const int* __restrict__ dst,
                                                    int* __restrict__ counts, int E) {
    int e = blockIdx.x * 256 + threadIdx.x;
    if (e < E) atomicAdd(&counts[dst[e]], 1);
}

// ---- hierarchical scan: 1024 elements per block, 256 threads x 4 ----
__global__ __launch_bounds__(256) void scan_bsums_kernel(const int* __restrict__ counts,
                                                         int* __restrict__ bsums, int N) {
    int t = threadIdx.x;
    int base = blockIdx.x * 1024 + t * 4;
    int s = 0;
    #pragma unroll
    for (int i = 0; i < 4; ++i) { int idx = base + i; if (idx < N) s += counts[idx]; }
    #pragma unroll
    for (int d = 1; d < 64; d <<= 1) s += __shfl_xor(s, d);
    __shared__ int ws[4];
    if ((t & 63) == 0) ws[t >> 6] = s;
    __syncthreads();
    if (t == 0) bsums[blockIdx.x] = ws[0] + ws[1] + ws[2] + ws[3];
}

// single-wave exclusive scan of block sums (NB <= 64)
__global__ __launch_bounds__(64) void scan_bscan_kernel(int* __restrict__ bsums, int NB) {
    int t = threadIdx.x;
    int v = (t < NB) ? bsums[t] : 0;
    int x = v;
    #pragma unroll
    for (int d = 1; d < 64; d <<= 1) {
        int y = __shfl_up(x, d);
        if (t >= d) x += y;
    }
    if (t < NB) bsums[t] = x - v;   // exclusive
}

__global__ __launch_bounds__(256) void scan_final_kernel(const int* __restrict__ counts,
                                                         const int* __restrict__ bsums,
                                                         int* __restrict__ offs, int N) {
    int t = threadIdx.x, lane = t & 63, w = t >> 6;
    int base = blockIdx.x * 1024 + t * 4;
    int v[4]; int s = 0;
    #pragma unroll
    for (int i = 0; i < 4; ++i) { int idx = base + i; v[i] = (idx < N) ? counts[idx] : 0; s += v[i]; }
    int x = s;
    #pragma unroll
    for (int d = 1; d < 64; d <<= 1) {
        int y = __shfl_up(x, d);
        if (lane >= d) x += y;
    }
    __shared__ int wtot[4];
    if (lane == 63) wtot[w] = x;
    __syncthreads();
    int wexc = 0;
    for (int i = 0; i < w; ++i) wexc += wtot[i];
    int run = (x - s) + wexc + bsums[blockIdx.x];  // exclusive prefix of this thread's first elem
    #pragma unroll
    for (int i = 0; i < 4; ++i) {
        int idx = base + i;
        run += v[i];
        if (idx < N) offs[idx + 1] = run;
    }
    if (blockIdx.x == 0 && t == 0) offs[0] = 0;
}

__global__ __launch_bounds__(256) void scatter_kernel(
    const int* __restrict__ src, const int* __restrict__ dst,
    const int* __restrict__ offs, int* __restrict__ cursor,
    int* __restrict__ csr_src, int* __restrict__ csr_eid, int E) {
    int e = blockIdx.x * 256 + threadIdx.x;
    if (e >= E) return;
    int d = dst[e];
    int pos = offs[d] + atomicAdd(&cursor[d], 1);
    csr_src[pos] = src[e];
    csr_eid[pos] = e;
}

// ---------------- per-layer kernels ----------------
// xl = hin @ Wl + bl ; xr = hin @ Wr + br   (D=64)
// 8 rows per wave amortizes the 32 KB LDS weight staging (12500 -> 1563 blocks)
#define ROWS_PER_WAVE 8
__global__ __launch_bounds__(256) void node_gemm_kernel(
    const float* __restrict__ hin,
    const float* __restrict__ Wl, const float* __restrict__ bl,
    const float* __restrict__ Wr, const float* __restrict__ br,
    float* __restrict__ xl, float* __restrict__ xr, int nrows)
{
    __shared__ float sWl[4096];
    __shared__ float sWr[4096];
    int t = threadIdx.x;
    {
        float4* dl = (float4*)sWl; const float4* sl = (const float4*)Wl;
        float4* dr = (float4*)sWr; const float4* sr = (const float4*)Wr;
        for (int i = t; i < 1024; i += 256) { dl[i] = sl[i]; dr[i] = sr[i]; }
    }
    __syncthreads();
    int lane = t & 63;
    int wave = t >> 6;
    int row0 = (blockIdx.x * 4 + wave) * ROWS_PER_WAVE;
    float xv[ROWS_PER_WAVE];
    #pragma unroll
    for (int r = 0; r < ROWS_PER_WAVE; ++r) {
        int row = row0 + r;
        xv[r] = (row < nrows) ? hin[(size_t)row * 64 + lane] : 0.f;
    }
    float b_l = bl[lane], b_r = br[lane];
    #pragma unroll
    for (int r = 0; r < ROWS_PER_WAVE; ++r) {
        int row = row0 + r;
        if (row >= nrows) break;
        float accl = b_l;
        float accr = b_r;
        #pragma unroll
        for (int k = 0; k < 64; ++k) {
            float xk = __shfl(xv[r], k);
            accl += xk * sWl[k * 64 + lane];
            accr += xk * sWr[k * 64 + lane];
        }
        xl[(size_t)row * 64 + lane] = accl;
        xr[(size_t)row * 64 + lane] = accr;
    }
}

// one thread per (edge, head): score only (no atomics)
__global__ __launch_bounds__(256) void edge_score_kernel(
    const float* __restrict__ xl, const float* __restrict__ xr,
    const float* __restrict__ ea,
    const int* __restrict__ src, const int* __restrict__ dst,
    const float* __restrict__ We, const float* __restrict__ att,
    float* __restrict__ score, int E)
{
    __shared__ float sWe[1024];   // 16 x 64
    __shared__ float sAtt[64];    // 4 x 16
    int t = threadIdx.x;
    for (int i = t; i < 1024; i += 256) sWe[i] = We[i];
    if (t < 64) sAtt[t] = att[t];
    __syncthreads();
    int gid = blockIdx.x * 256 + t;
    int e = gid >> 2, h = gid & 3;
    if (e >= E) return;
    int s = src[e], d = dst[e];
    const float4* eap = (const float4*)(ea + (size_t)e * 16);
    float4 a0 = eap[0], a1 = eap[1], a2 = eap[2], a3 = eap[3];
    float av[16] = {a0.x, a0.y, a0.z, a0.w, a1.x, a1.y, a1.z, a1.w,
                    a2.x, a2.y, a2.z, a2.w, a3.x, a3.y, a3.z, a3.w};
    const float4* xls = (const float4*)(xl + (size_t)s * 64 + h * 16);
    const float4* xrd = (const float4*)(xr + (size_t)d * 64 + h * 16);
    float sc = 0.f;
    #pragma unroll
    for (int q = 0; q < 4; ++q) {
        float4 vl = xls[q];
        float4 vr = xrd[q];
        float lv[4] = {vl.x, vl.y, vl.z, vl.w};
        float rv[4] = {vr.x, vr.y, vr.z, vr.w};
        #pragma unroll
        for (int j = 0; j < 4; ++j) {
            int c = q * 4 + j;
            float ef = 0.f;
            #pragma unroll
            for (int k = 0; k < 16; ++k) ef += av[k] * sWe[k * 64 + h * 16 + c];
            float m = lv[j] + rv[j] + ef;
            m = (m >= 0.f) ? m : NEG_SLOPE * m;
            sc += m * sAtt[h * 16 + c];
        }
    }
    score[gid] = sc;
}

// one wave per node: max over in-edges, then double-accumulated softmax aggregate
__global__ __launch_bounds__(256) void node_pass_kernel(
    const float* __restrict__ score, const float* __restrict__ xl,
    const int* __restrict__ csr_src, const int* __restrict__ csr_eid,
    const int* __restrict__ offs, const float* __restrict__ bias,
    float* __restrict__ hout, int N)
{
    int t = threadIdx.x;
    int lane = t & 63;
    int node = blockIdx.x * 4 + (t >> 6);
    if (node >= N) return;
    int h = lane >> 4;
    int off = offs[node];
    int deg = offs[node + 1] - off;

    // pass 1: max score for this head (order-invariant)
    float mx = -FLT_MAX;
    for (int base = 0; base < deg; base += 64) {
        int lim = deg - base; if (lim > 64) lim = 64;
        int eidv = 0;
        if (lane < lim) eidv = csr_eid[off + base + lane];
        for (int j = 0; j < lim; ++j) {
            int e = __shfl(eidv, j);
            float sc = score[(size_t)e * 4 + h];
            mx = fmaxf(mx, sc);
        }
    }

    // pass 2: double accumulation (order jitter ~1e-16 only)
    double sSum = 0.0, O = 0.0;
    for (int base = 0; base < deg; base += 64) {
        int lim = deg - base; if (lim > 64) lim = 64;
        int eidv = 0, srcv = 0;
        if (lane < lim) {
            eidv = csr_eid[off + base + lane];
            srcv = csr_src[off + base + lane];
        }
        for (int j = 0; j < lim; ++j) {
            int e = __shfl(eidv, j);
            int s = __shfl(srcv, j);
            float sc = score[(size_t)e * 4 + h];
            float ex = expf(sc - mx);
            sSum += (double)ex;
            O += (double)ex * (double)xl[(size_t)s * 64 + lane];
        }
    }

    float v = (deg > 0) ? (float)(O / sSum) : 0.f;
    v += bias[lane];
    hout[(size_t)node * 64 + lane] = fmaxf(v, 0.f);
}

extern "C" void kernel_launch(void* const* d_in, const int* in_sizes, int n_in,
                              void* d_out, int out_size, void* d_ws, size_t ws_size,
                              hipStream_t stream) {
    const float* x    = (const float*)d_in[0];
    const int*   eidx = (const int*)d_in[1];
    const float* ea   = (const float*)d_in[2];
    const float* Wl   = (const float*)d_in[3];
    const float* bl   = (const float*)d_in[4];
    const float* Wr   = (const float*)d_in[5];
    const float* br   = (const float*)d_in[6];
    const float* We   = (const float*)d_in[7];
    const float* att  = (const float*)d_in[8];
    const float* bias = (const float*)d_in[9];
    float* out = (float*)d_out;

    const int N = in_sizes[0] / 64;
    const int E = in_sizes[1] / 2;
    const int* src = eidx;
    const int* dst = eidx + E;

    float* ws = (float*)d_ws;
    float* xl      = ws;                               // N*64
    float* xr      = xl + (size_t)N * 64;              // N*64
    float* score   = xr + (size_t)N * 64;              // E*4
    float* h_tmp   = score + (size_t)E * 4;            // N*64
    int* counts    = (int*)(h_tmp + (size_t)N * 64);   // N
    int* cursor    = counts + N;                       // N
    int* offs      = cursor + N;                       // N+1
    int* csr_src   = offs + N + 1;                     // E
    int* csr_eid   = csr_src + E;                      // E
    int* bsums     = csr_eid + E;                      // ~64

    dim3 blk(256);
    int g_n    = (N + 255) / 256;
    int g_e    = (E + 255) / 256;
    int g_eh   = (E * 4 + 255) / 256;
    int g_gemm = (N + 4 * ROWS_PER_WAVE - 1) / (4 * ROWS_PER_WAVE);
    int g_node = (N + 3) / 4;
    int NB     = (N + 1023) / 1024;   // 49 for N=50000 (must be <= 64)

    // CSR over dst (edge_index is layer-invariant)
    zero_kernel<<<g_n, blk, 0, stream>>>(counts, cursor, N);
    count_kernel<<<g_e, blk, 0, stream>>>(dst, counts, E);
    scan_bsums_kernel<<<NB, blk, 0, stream>>>(counts, bsums, N);
    scan_bscan_kernel<<<1, 64, 0, stream>>>(bsums, NB);
    scan_final_kernel<<<NB, blk, 0, stream>>>(counts, bsums, offs, N);
    scatter_kernel<<<g_e, blk, 0, stream>>>(src, dst, offs, cursor, csr_src, csr_eid, E);

    const float* hin = x;
    for (int l = 0; l < 3; ++l) {
        float* hout = (l == 2) ? out : h_tmp;
        node_gemm_kernel<<<g_gemm, blk, 0, stream>>>(hin, Wl + (size_t)l * 4096, bl + l * 64,
                                                     Wr + (size_t)l * 4096, br + l * 64, xl, xr, N);
        edge_score_kernel<<<g_eh, blk, 0, stream>>>(xl, xr, ea, src, dst,
                                                    We + (size_t)l * 1024, att + l * 64,
                                                    score, E);
        node_pass_kernel<<<g_node, blk, 0, stream>>>(score, xl, csr_src, csr_eid, offs,
                                                     bias + l * 64, hout, N);
        hin = hout;
    }
}

// Round 10
// 824.719 us; speedup vs baseline: 1.1749x; 1.0407x over previous
//
#include <hip/hip_runtime.h>
#include <cfloat>

#define NEG_SLOPE 0.2f

// ---------------- CSR build ----------------
__global__ __launch_bounds__(256) void zero_kernel(int* __restrict__ counts,
                                                   int* __restrict__ cursor, int n) {
    int gid = blockIdx.x * 256 + threadIdx.x;
    if (gid < n) { counts[gid] = 0; cursor[gid] = 0; }
}

__global__ __launch_bounds__(256) void count_kernel(const int* __restrict__ dst,
                                                    int* __restrict__ counts, int E) {
    int e = blockIdx.x * 256 + threadIdx.x;
    if (e < E) atomicAdd(&counts[dst[e]], 1);
}

// ---- hierarchical scan: 1024 elements per block ----
__global__ __launch_bounds__(256) void scan_bsums_kernel(const int* __restrict__ counts,
                                                         int* __restrict__ bsums, int N) {
    int t = threadIdx.x;
    int base = blockIdx.x * 1024 + t * 4;
    int s = 0;
    #pragma unroll
    for (int i = 0; i < 4; ++i) { int idx = base + i; if (idx < N) s += counts[idx]; }
    #pragma unroll
    for (int d = 1; d < 64; d <<= 1) s += __shfl_xor(s, d);
    __shared__ int ws[4];
    if ((t & 63) == 0) ws[t >> 6] = s;
    __syncthreads();
    if (t == 0) bsums[blockIdx.x] = ws[0] + ws[1] + ws[2] + ws[3];
}

__global__ __launch_bounds__(64) void scan_bscan_kernel(int* __restrict__ bsums, int NB) {
    int t = threadIdx.x;
    int v = (t < NB) ? bsums[t] : 0;
    int x = v;
    #pragma unroll
    for (int d = 1; d < 64; d <<= 1) {
        int y = __shfl_up(x, d);
        if (t >= d) x += y;
    }
    if (t < NB) bsums[t] = x - v;   // exclusive
}

__global__ __launch_bounds__(256) void scan_final_kernel(const int* __restrict__ counts,
                                                         const int* __restrict__ bsums,
                                                         int* __restrict__ offs, int N) {
    int t = threadIdx.x, lane = t & 63, w = t >> 6;
    int base = blockIdx.x * 1024 + t * 4;
    int v[4]; int s = 0;
    #pragma unroll
    for (int i = 0; i < 4; ++i) { int idx = base + i; v[i] = (idx < N) ? counts[idx] : 0; s += v[i]; }
    int x = s;
    #pragma unroll
    for (int d = 1; d < 64; d <<= 1) {
        int y = __shfl_up(x, d);
        if (lane >= d) x += y;
    }
    __shared__ int wtot[4];
    if (lane == 63) wtot[w] = x;
    __syncthreads();
    int wexc = 0;
    for (int i = 0; i < w; ++i) wexc += wtot[i];
    int run = (x - s) + wexc + bsums[blockIdx.x];
    #pragma unroll
    for (int i = 0; i < 4; ++i) {
        int idx = base + i;
        run += v[i];
        if (idx < N) offs[idx + 1] = run;
    }
    if (blockIdx.x == 0 && t == 0) offs[0] = 0;
}

__global__ __launch_bounds__(256) void scatter_kernel(
    const int* __restrict__ src, const int* __restrict__ dst,
    const int* __restrict__ offs, int* __restrict__ cursor,
    int* __restrict__ csr_src, int* __restrict__ csr_dst,
    int* __restrict__ csr_eid, int E) {
    int e = blockIdx.x * 256 + threadIdx.x;
    if (e >= E) return;
    int d = dst[e];
    int pos = offs[d] + atomicAdd(&cursor[d], 1);
    csr_src[pos] = src[e];
    csr_dst[pos] = d;
    csr_eid[pos] = e;
}

// ---------------- per-layer kernels ----------------
#define ROWS_PER_WAVE 8
__global__ __launch_bounds__(256) void node_gemm_kernel(
    const float* __restrict__ hin,
    const float* __restrict__ Wl, const float* __restrict__ bl,
    const float* __restrict__ Wr, const float* __restrict__ br,
    float* __restrict__ xl, float* __restrict__ xr, int nrows)
{
    __shared__ float sWl[4096];
    __shared__ float sWr[4096];
    int t = threadIdx.x;
    {
        float4* dl = (float4*)sWl; const float4* sl = (const float4*)Wl;
        float4* dr = (float4*)sWr; const float4* sr = (const float4*)Wr;
        for (int i = t; i < 1024; i += 256) { dl[i] = sl[i]; dr[i] = sr[i]; }
    }
    __syncthreads();
    int lane = t & 63;
    int wave = t >> 6;
    int row0 = (blockIdx.x * 4 + wave) * ROWS_PER_WAVE;
    float xv[ROWS_PER_WAVE];
    #pragma unroll
    for (int r = 0; r < ROWS_PER_WAVE; ++r) {
        int row = row0 + r;
        xv[r] = (row < nrows) ? hin[(size_t)row * 64 + lane] : 0.f;
    }
    float b_l = bl[lane], b_r = br[lane];
    #pragma unroll
    for (int r = 0; r < ROWS_PER_WAVE; ++r) {
        int row = row0 + r;
        if (row >= nrows) break;
        float accl = b_l;
        float accr = b_r;
        #pragma unroll
        for (int k = 0; k < 64; ++k) {
            float xk = __shfl(xv[r], k);
            accl += xk * sWl[k * 64 + lane];
            accr += xk * sWr[k * 64 + lane];
        }
        xl[(size_t)row * 64 + lane] = accl;
        xr[(size_t)row * 64 + lane] = accr;
    }
}

// one thread per (CSR position, head): coalesced score_csr writes; xr[dst] segment-constant
__global__ __launch_bounds__(256) void edge_score_kernel(
    const float* __restrict__ xl, const float* __restrict__ xr,
    const float* __restrict__ ea,
    const int* __restrict__ csr_src, const int* __restrict__ csr_dst,
    const int* __restrict__ csr_eid,
    const float* __restrict__ We, const float* __restrict__ att,
    float* __restrict__ score_csr, int E)
{
    __shared__ float sWe[1024];   // 16 x 64
    __shared__ float sAtt[64];    // 4 x 16
    int t = threadIdx.x;
    for (int i = t; i < 1024; i += 256) sWe[i] = We[i];
    if (t < 64) sAtt[t] = att[t];
    __syncthreads();
    int gid = blockIdx.x * 256 + t;
    int pos = gid >> 2, h = gid & 3;
    if (pos >= E) return;
    int s = csr_src[pos], d = csr_dst[pos], eid = csr_eid[pos];
    const float4* eap = (const float4*)(ea + (size_t)eid * 16);
    float4 a0 = eap[0], a1 = eap[1], a2 = eap[2], a3 = eap[3];
    float av[16] = {a0.x, a0.y, a0.z, a0.w, a1.x, a1.y, a1.z, a1.w,
                    a2.x, a2.y, a2.z, a2.w, a3.x, a3.y, a3.z, a3.w};
    const float4* xls = (const float4*)(xl + (size_t)s * 64 + h * 16);
    const float4* xrd = (const float4*)(xr + (size_t)d * 64 + h * 16);
    float sc = 0.f;
    #pragma unroll
    for (int q = 0; q < 4; ++q) {
        float4 vl = xls[q];
        float4 vr = xrd[q];
        float lv[4] = {vl.x, vl.y, vl.z, vl.w};
        float rv[4] = {vr.x, vr.y, vr.z, vr.w};
        #pragma unroll
        for (int j = 0; j < 4; ++j) {
            int c = q * 4 + j;
            float ef = 0.f;
            #pragma unroll
            for (int k = 0; k < 16; ++k) ef += av[k] * sWe[k * 64 + h * 16 + c];
            float m = lv[j] + rv[j] + ef;
            m = (m >= 0.f) ? m : NEG_SLOPE * m;
            sc += m * sAtt[h * 16 + c];
        }
    }
    score_csr[gid] = sc;
}

// one BLOCK (4 waves) per node: waves split edges; deterministic fixed-order combine
__global__ __launch_bounds__(256) void node_pass_kernel(
    const float* __restrict__ score_csr, const float* __restrict__ xl,
    const int* __restrict__ csr_src,
    const int* __restrict__ offs, const float* __restrict__ bias,
    float* __restrict__ hout, int N)
{
    int node = blockIdx.x;
    int t = threadIdx.x;
    int lane = t & 63;
    int w = t >> 6;
    int h = lane >> 4;
    int off = offs[node];
    int deg = offs[node + 1] - off;

    // pass 1: per-wave max over strided edges (exact, order-free)
    float mx = -FLT_MAX;
    for (int j = w; j < deg; j += 4) {
        float sc = score_csr[(size_t)(off + j) * 4 + h];
        mx = fmaxf(mx, sc);
    }
    __shared__ float smx[4][4];   // [wave][head]
    if ((lane & 15) == 0) smx[w][h] = mx;
    __syncthreads();
    mx = fmaxf(fmaxf(smx[0][h], smx[1][h]), fmaxf(smx[2][h], smx[3][h]));

    // pass 2: per-wave double partials over strided edges
    double sSum = 0.0, O = 0.0;
    for (int j = w; j < deg; j += 4) {
        int pos = off + j;
        int s = csr_src[pos];                       // wave-uniform broadcast
        float sc = score_csr[(size_t)pos * 4 + h];
        float ex = expf(sc - mx);
        sSum += (double)ex;
        O += (double)ex * (double)xl[(size_t)s * 64 + lane];
    }

    // deterministic fixed-order combine across the 4 waves
    __shared__ double sO[4][64];
    __shared__ double sS[4][4];
    sO[w][lane] = O;
    if ((lane & 15) == 0) sS[w][h] = sSum;
    __syncthreads();
    if (w == 0) {
        double Ot = ((sO[0][lane] + sO[1][lane]) + sO[2][lane]) + sO[3][lane];
        double St = ((sS[0][h] + sS[1][h]) + sS[2][h]) + sS[3][h];
        float v = (deg > 0) ? (float)(Ot / St) : 0.f;
        v += bias[lane];
        hout[(size_t)node * 64 + lane] = fmaxf(v, 0.f);
    }
}

extern "C" void kernel_launch(void* const* d_in, const int* in_sizes, int n_in,
                              void* d_out, int out_size, void* d_ws, size_t ws_size,
                              hipStream_t stream) {
    const float* x    = (const float*)d_in[0];
    const int*   eidx = (const int*)d_in[1];
    const float* ea   = (const float*)d_in[2];
    const float* Wl   = (const float*)d_in[3];
    const float* bl   = (const float*)d_in[4];
    const float* Wr   = (const float*)d_in[5];
    const float* br   = (const float*)d_in[6];
    const float* We   = (const float*)d_in[7];
    const float* att  = (const float*)d_in[8];
    const float* bias = (const float*)d_in[9];
    float* out = (float*)d_out;

    const int N = in_sizes[0] / 64;
    const int E = in_sizes[1] / 2;
    const int* src = eidx;
    const int* dst = eidx + E;

    float* ws = (float*)d_ws;
    float* xl      = ws;                               // N*64
    float* xr      = xl + (size_t)N * 64;              // N*64
    float* score   = xr + (size_t)N * 64;              // E*4 (CSR-indexed)
    float* h_tmp   = score + (size_t)E * 4;            // N*64
    int* counts    = (int*)(h_tmp + (size_t)N * 64);   // N
    int* cursor    = counts + N;                       // N
    int* offs      = cursor + N;                       // N+1
    int* csr_src   = offs + N + 1;                     // E
    int* csr_dst   = csr_src + E;                      // E
    int* csr_eid   = csr_dst + E;                      // E
    int* bsums     = csr_eid + E;                      // ~64

    dim3 blk(256);
    int g_n    = (N + 255) / 256;
    int g_e    = (E + 255) / 256;
    int g_eh   = (E * 4 + 255) / 256;
    int g_gemm = (N + 4 * ROWS_PER_WAVE - 1) / (4 * ROWS_PER_WAVE);
    int NB     = (N + 1023) / 1024;   // 49 for N=50000 (<= 64)

    // CSR over dst (edge_index is layer-invariant)
    zero_kernel<<<g_n, blk, 0, stream>>>(counts, cursor, N);
    count_kernel<<<g_e, blk, 0, stream>>>(dst, counts, E);
    scan_bsums_kernel<<<NB, blk, 0, stream>>>(counts, bsums, N);
    scan_bscan_kernel<<<1, 64, 0, stream>>>(bsums, NB);
    scan_final_kernel<<<NB, blk, 0, stream>>>(counts, bsums, offs, N);
    scatter_kernel<<<g_e, blk, 0, stream>>>(src, dst, offs, cursor,
                                            csr_src, csr_dst, csr_eid, E);

    const float* hin = x;
    for (int l = 0; l < 3; ++l) {
        float* hout = (l == 2) ? out : h_tmp;
        node_gemm_kernel<<<g_gemm, blk, 0, stream>>>(hin, Wl + (size_t)l * 4096, bl + l * 64,
                                                     Wr + (size_t)l * 4096, br + l * 64, xl, xr, N);
        edge_score_kernel<<<g_eh, blk, 0, stream>>>(xl, xr, ea, csr_src, csr_dst, csr_eid,
                                                    We + (size_t)l * 1024, att + l * 64,
                                                    score, E);
        node_pass_kernel<<<N, blk, 0, stream>>>(score, xl, csr_src, offs,
                                                bias + l * 64, hout, N);
        hin = hout;
    }
}

// Round 11
// 671.414 us; speedup vs baseline: 1.4431x; 1.2283x over previous
//
#include <hip/hip_runtime.h>
#include <cfloat>

#define NEG_SLOPE 0.2f

// ---------------- CSR build ----------------
__global__ __launch_bounds__(256) void zero_kernel(int* __restrict__ counts,
                                                   int* __restrict__ cursor, int n) {
    int gid = blockIdx.x * 256 + threadIdx.x;
    if (gid < n) { counts[gid] = 0; cursor[gid] = 0; }
}

__global__ __launch_bounds__(256) void count_kernel(const int* __restrict__ dst,
                                                    int* __restrict__ counts, int E) {
    int e = blockIdx.x * 256 + threadIdx.x;
    if (e < E) atomicAdd(&counts[dst[e]], 1);
}

// ---- hierarchical scan: 1024 elements per block ----
__global__ __launch_bounds__(256) void scan_bsums_kernel(const int* __restrict__ counts,
                                                         int* __restrict__ bsums, int N) {
    int t = threadIdx.x;
    int base = blockIdx.x * 1024 + t * 4;
    int s = 0;
    #pragma unroll
    for (int i = 0; i < 4; ++i) { int idx = base + i; if (idx < N) s += counts[idx]; }
    #pragma unroll
    for (int d = 1; d < 64; d <<= 1) s += __shfl_xor(s, d);
    __shared__ int ws[4];
    if ((t & 63) == 0) ws[t >> 6] = s;
    __syncthreads();
    if (t == 0) bsums[blockIdx.x] = ws[0] + ws[1] + ws[2] + ws[3];
}

__global__ __launch_bounds__(64) void scan_bscan_kernel(int* __restrict__ bsums, int NB) {
    int t = threadIdx.x;
    int v = (t < NB) ? bsums[t] : 0;
    int x = v;
    #pragma unroll
    for (int d = 1; d < 64; d <<= 1) {
        int y = __shfl_up(x, d);
        if (t >= d) x += y;
    }
    if (t < NB) bsums[t] = x - v;   // exclusive
}

__global__ __launch_bounds__(256) void scan_final_kernel(const int* __restrict__ counts,
                                                         const int* __restrict__ bsums,
                                                         int* __restrict__ offs, int N) {
    int t = threadIdx.x, lane = t & 63, w = t >> 6;
    int base = blockIdx.x * 1024 + t * 4;
    int v[4]; int s = 0;
    #pragma unroll
    for (int i = 0; i < 4; ++i) { int idx = base + i; v[i] = (idx < N) ? counts[idx] : 0; s += v[i]; }
    int x = s;
    #pragma unroll
    for (int d = 1; d < 64; d <<= 1) {
        int y = __shfl_up(x, d);
        if (lane >= d) x += y;
    }
    __shared__ int wtot[4];
    if (lane == 63) wtot[w] = x;
    __syncthreads();
    int wexc = 0;
    for (int i = 0; i < w; ++i) wexc += wtot[i];
    int run = (x - s) + wexc + bsums[blockIdx.x];
    #pragma unroll
    for (int i = 0; i < 4; ++i) {
        int idx = base + i;
        run += v[i];
        if (idx < N) offs[idx + 1] = run;
    }
    if (blockIdx.x == 0 && t == 0) offs[0] = 0;
}

__global__ __launch_bounds__(256) void scatter_kernel(
    const int* __restrict__ src, const int* __restrict__ dst,
    const int* __restrict__ offs, int* __restrict__ cursor,
    int* __restrict__ csr_src, int* __restrict__ csr_dst,
    int* __restrict__ csr_eid, int E) {
    int e = blockIdx.x * 256 + threadIdx.x;
    if (e >= E) return;
    int d = dst[e];
    int pos = offs[d] + atomicAdd(&cursor[d], 1);
    csr_src[pos] = src[e];
    csr_dst[pos] = d;
    csr_eid[pos] = e;
}

// canonical order: sort each dst-segment by eid (one wave per node, in-place, rank sort)
__global__ __launch_bounds__(256) void sort_segments_kernel(
    int* __restrict__ csr_src, int* __restrict__ csr_eid,
    const int* __restrict__ offs, int N)
{
    int t = threadIdx.x;
    int lane = t & 63;
    int node = blockIdx.x * 4 + (t >> 6);
    if (node >= N) return;
    int off = offs[node];
    int deg = offs[node + 1] - off;
    if (deg <= 1) return;
    if (deg <= 64) {
        int key = 0x7FFFFFFF, val = 0;
        if (lane < deg) { key = csr_eid[off + lane]; val = csr_src[off + lane]; }
        int rank = 0;
        #pragma unroll
        for (int i = 0; i < 64; ++i) {
            int ki = __shfl(key, i);
            if (ki < key) rank++;            // eids unique -> permutation
        }
        if (lane < deg) { csr_eid[off + rank] = key; csr_src[off + rank] = val; }
    } else if (lane == 0) {
        // practically unreachable (Poisson deg ~16); serial insertion sort
        for (int a = 1; a < deg; ++a) {
            int k = csr_eid[off + a], v = csr_src[off + a];
            int b = a - 1;
            while (b >= 0 && csr_eid[off + b] > k) {
                csr_eid[off + b + 1] = csr_eid[off + b];
                csr_src[off + b + 1] = csr_src[off + b];
                b--;
            }
            csr_eid[off + b + 1] = k;
            csr_src[off + b + 1] = v;
        }
    }
}

// ---------------- per-layer kernels ----------------
#define ROWS_PER_WAVE 8
__global__ __launch_bounds__(256) void node_gemm_kernel(
    const float* __restrict__ hin,
    const float* __restrict__ Wl, const float* __restrict__ bl,
    const float* __restrict__ Wr, const float* __restrict__ br,
    float* __restrict__ xl, float* __restrict__ xr, int nrows)
{
    __shared__ float sWl[4096];
    __shared__ float sWr[4096];
    int t = threadIdx.x;
    {
        float4* dl = (float4*)sWl; const float4* sl = (const float4*)Wl;
        float4* dr = (float4*)sWr; const float4* sr = (const float4*)Wr;
        for (int i = t; i < 1024; i += 256) { dl[i] = sl[i]; dr[i] = sr[i]; }
    }
    __syncthreads();
    int lane = t & 63;
    int wave = t >> 6;
    int row0 = (blockIdx.x * 4 + wave) * ROWS_PER_WAVE;
    float xv[ROWS_PER_WAVE];
    #pragma unroll
    for (int r = 0; r < ROWS_PER_WAVE; ++r) {
        int row = row0 + r;
        xv[r] = (row < nrows) ? hin[(size_t)row * 64 + lane] : 0.f;
    }
    float b_l = bl[lane], b_r = br[lane];
    #pragma unroll
    for (int r = 0; r < ROWS_PER_WAVE; ++r) {
        int row = row0 + r;
        if (row >= nrows) break;
        float accl = b_l;
        float accr = b_r;
        #pragma unroll
        for (int k = 0; k < 64; ++k) {
            float xk = __shfl(xv[r], k);
            accl += xk * sWl[k * 64 + lane];
            accr += xk * sWr[k * 64 + lane];
        }
        xl[(size_t)row * 64 + lane] = accl;
        xr[(size_t)row * 64 + lane] = accr;
    }
}

// one thread per (CSR position, head): coalesced score_csr writes; xr[dst] segment-constant
__global__ __launch_bounds__(256) void edge_score_kernel(
    const float* __restrict__ xl, const float* __restrict__ xr,
    const float* __restrict__ ea,
    const int* __restrict__ csr_src, const int* __restrict__ csr_dst,
    const int* __restrict__ csr_eid,
    const float* __restrict__ We, const float* __restrict__ att,
    float* __restrict__ score_csr, int E)
{
    __shared__ float sWe[1024];   // 16 x 64
    __shared__ float sAtt[64];    // 4 x 16
    int t = threadIdx.x;
    for (int i = t; i < 1024; i += 256) sWe[i] = We[i];
    if (t < 64) sAtt[t] = att[t];
    __syncthreads();
    int gid = blockIdx.x * 256 + t;
    int pos = gid >> 2, h = gid & 3;
    if (pos >= E) return;
    int s = csr_src[pos], d = csr_dst[pos], eid = csr_eid[pos];
    const float4* eap = (const float4*)(ea + (size_t)eid * 16);
    float4 a0 = eap[0], a1 = eap[1], a2 = eap[2], a3 = eap[3];
    float av[16] = {a0.x, a0.y, a0.z, a0.w, a1.x, a1.y, a1.z, a1.w,
                    a2.x, a2.y, a2.z, a2.w, a3.x, a3.y, a3.z, a3.w};
    const float4* xls = (const float4*)(xl + (size_t)s * 64 + h * 16);
    const float4* xrd = (const float4*)(xr + (size_t)d * 64 + h * 16);
    float sc = 0.f;
    #pragma unroll
    for (int q = 0; q < 4; ++q) {
        float4 vl = xls[q];
        float4 vr = xrd[q];
        float lv[4] = {vl.x, vl.y, vl.z, vl.w};
        float rv[4] = {vr.x, vr.y, vr.z, vr.w};
        #pragma unroll
        for (int j = 0; j < 4; ++j) {
            int c = q * 4 + j;
            float ef = 0.f;
            #pragma unroll
            for (int k = 0; k < 16; ++k) ef += av[k] * sWe[k * 64 + h * 16 + c];
            float m = lv[j] + rv[j] + ef;
            m = (m >= 0.f) ? m : NEG_SLOPE * m;
            sc += m * sAtt[h * 16 + c];
        }
    }
    score_csr[gid] = sc;
}

// one WAVE per node; lane = (edge-slot eg 0..3, channel-quad k 0..15, head = k>>2)
// 4 edges per iteration; f32 accumulation in canonical (eid-sorted) CSR order.
__global__ __launch_bounds__(256) void node_pass_kernel(
    const float* __restrict__ score_csr, const float* __restrict__ xl,
    const int* __restrict__ csr_src,
    const int* __restrict__ offs, const float* __restrict__ bias,
    float* __restrict__ hout, int N)
{
    int t = threadIdx.x;
    int lane = t & 63;
    int node = blockIdx.x * 4 + (t >> 6);
    if (node >= N) return;
    int eg = lane >> 4;          // edge slot
    int k  = lane & 15;          // channel quad; channels [4k,4k+3]; head = k>>2
    int h  = k >> 2;
    int off = offs[node];
    int deg = offs[node + 1] - off;

    if (deg == 0) {
        if (eg == 0) {
            float4 b = *(const float4*)(bias + k * 4);
            float4 o;
            o.x = fmaxf(b.x, 0.f); o.y = fmaxf(b.y, 0.f);
            o.z = fmaxf(b.z, 0.f); o.w = fmaxf(b.w, 0.f);
            *(float4*)(hout + (size_t)node * 64 + k * 4) = o;
        }
        return;
    }

    // pass 1: head max (exact, order-free)
    float mx = -FLT_MAX;
    for (int j0 = 0; j0 < deg; j0 += 4) {
        int j = j0 + eg;
        if (j < deg) {
            float sc = score_csr[(size_t)(off + j) * 4 + h];
            mx = fmaxf(mx, sc);
        }
    }
    mx = fmaxf(mx, __shfl_xor(mx, 16));
    mx = fmaxf(mx, __shfl_xor(mx, 32));

    // pass 2: 4 edges per iteration, float4 FMA payload
    float4 acc = {0.f, 0.f, 0.f, 0.f};
    float sSum = 0.f;
    for (int j0 = 0; j0 < deg; j0 += 4) {
        int j = j0 + eg;
        int jj = (j < deg) ? j : deg - 1;
        int pos = off + jj;
        int s = csr_src[pos];
        float sc = score_csr[(size_t)pos * 4 + h];
        float ex = (j < deg) ? __expf(sc - mx) : 0.f;
        float4 v = *(const float4*)(xl + (size_t)s * 64 + k * 4);
        acc.x += ex * v.x; acc.y += ex * v.y;
        acc.z += ex * v.z; acc.w += ex * v.w;
        sSum += ex;
    }

    // fixed-grouping butterfly reduce across edge slots (deterministic)
    acc.x += __shfl_xor(acc.x, 16); acc.y += __shfl_xor(acc.y, 16);
    acc.z += __shfl_xor(acc.z, 16); acc.w += __shfl_xor(acc.w, 16);
    sSum  += __shfl_xor(sSum, 16);
    acc.x += __shfl_xor(acc.x, 32); acc.y += __shfl_xor(acc.y, 32);
    acc.z += __shfl_xor(acc.z, 32); acc.w += __shfl_xor(acc.w, 32);
    sSum  += __shfl_xor(sSum, 32);

    if (eg == 0) {
        float inv = 1.f / sSum;   // sSum >= 1 (max edge has ex = 1)
        float4 b = *(const float4*)(bias + k * 4);
        float4 o;
        o.x = fmaxf(acc.x * inv + b.x, 0.f);
        o.y = fmaxf(acc.y * inv + b.y, 0.f);
        o.z = fmaxf(acc.z * inv + b.z, 0.f);
        o.w = fmaxf(acc.w * inv + b.w, 0.f);
        *(float4*)(hout + (size_t)node * 64 + k * 4) = o;
    }
}

extern "C" void kernel_launch(void* const* d_in, const int* in_sizes, int n_in,
                              void* d_out, int out_size, void* d_ws, size_t ws_size,
                              hipStream_t stream) {
    const float* x    = (const float*)d_in[0];
    const int*   eidx = (const int*)d_in[1];
    const float* ea   = (const float*)d_in[2];
    const float* Wl   = (const float*)d_in[3];
    const float* bl   = (const float*)d_in[4];
    const float* Wr   = (const float*)d_in[5];
    const float* br   = (const float*)d_in[6];
    const float* We   = (const float*)d_in[7];
    const float* att  = (const float*)d_in[8];
    const float* bias = (const float*)d_in[9];
    float* out = (float*)d_out;

    const int N = in_sizes[0] / 64;
    const int E = in_sizes[1] / 2;
    const int* src = eidx;
    const int* dst = eidx + E;

    float* ws = (float*)d_ws;
    float* xl      = ws;                               // N*64
    float* xr      = xl + (size_t)N * 64;              // N*64
    float* score   = xr + (size_t)N * 64;              // E*4 (CSR-indexed)
    float* h_tmp   = score + (size_t)E * 4;            // N*64
    int* counts    = (int*)(h_tmp + (size_t)N * 64);   // N
    int* cursor    = counts + N;                       // N
    int* offs      = cursor + N;                       // N+1
    int* csr_src   = offs + N + 1;                     // E
    int* csr_dst   = csr_src + E;                      // E
    int* csr_eid   = csr_dst + E;                      // E
    int* bsums     = csr_eid + E;                      // ~64

    dim3 blk(256);
    int g_n    = (N + 255) / 256;
    int g_e    = (E + 255) / 256;
    int g_eh   = (E * 4 + 255) / 256;
    int g_gemm = (N + 4 * ROWS_PER_WAVE - 1) / (4 * ROWS_PER_WAVE);
    int g_node = (N + 3) / 4;
    int NB     = (N + 1023) / 1024;   // 49 for N=50000 (<= 64)

    // CSR over dst, canonical eid order (edge_index is layer-invariant)
    zero_kernel<<<g_n, blk, 0, stream>>>(counts, cursor, N);
    count_kernel<<<g_e, blk, 0, stream>>>(dst, counts, E);
    scan_bsums_kernel<<<NB, blk, 0, stream>>>(counts, bsums, N);
    scan_bscan_kernel<<<1, 64, 0, stream>>>(bsums, NB);
    scan_final_kernel<<<NB, blk, 0, stream>>>(counts, bsums, offs, N);
    scatter_kernel<<<g_e, blk, 0, stream>>>(src, dst, offs, cursor,
                                            csr_src, csr_dst, csr_eid, E);
    sort_segments_kernel<<<g_node, blk, 0, stream>>>(csr_src, csr_eid, offs, N);

    const float* hin = x;
    for (int l = 0; l < 3; ++l) {
        float* hout = (l == 2) ? out : h_tmp;
        node_gemm_kernel<<<g_gemm, blk, 0, stream>>>(hin, Wl + (size_t)l * 4096, bl + l * 64,
                                                     Wr + (size_t)l * 4096, br + l * 64, xl, xr, N);
        edge_score_kernel<<<g_eh, blk, 0, stream>>>(xl, xr, ea, csr_src, csr_dst, csr_eid,
                                                    We + (size_t)l * 1024, att + l * 64,
                                                    score, E);
        node_pass_kernel<<<g_node, blk, 0, stream>>>(score, xl, csr_src, offs,
                                                     bias + l * 64, hout, N);
        hin = hout;
    }
}

// Round 13
// 637.099 us; speedup vs baseline: 1.5209x; 1.0539x over previous
//
#include <hip/hip_runtime.h>
#include <cfloat>

#define NEG_SLOPE 0.2f

// ---------------- CSR build ----------------
__global__ __launch_bounds__(256) void zero_kernel(int* __restrict__ counts,
                                                   int* __restrict__ cursor, int n) {
    int gid = blockIdx.x * 256 + threadIdx.x;
    if (gid < n) { counts[gid] = 0; cursor[gid] = 0; }
}

__global__ __launch_bounds__(256) void count_kernel(const int* __restrict__ dst,
                                                    int* __restrict__ counts, int E) {
    int e = blockIdx.x * 256 + threadIdx.x;
    if (e < E) atomicAdd(&counts[dst[e]], 1);
}

// ---- hierarchical scan: 1024 elements per block ----
__global__ __launch_bounds__(256) void scan_bsums_kernel(const int* __restrict__ counts,
                                                         int* __restrict__ bsums, int N) {
    int t = threadIdx.x;
    int base = blockIdx.x * 1024 + t * 4;
    int s = 0;
    #pragma unroll
    for (int i = 0; i < 4; ++i) { int idx = base + i; if (idx < N) s += counts[idx]; }
    #pragma unroll
    for (int d = 1; d < 64; d <<= 1) s += __shfl_xor(s, d);
    __shared__ int ws[4];
    if ((t & 63) == 0) ws[t >> 6] = s;
    __syncthreads();
    if (t == 0) bsums[blockIdx.x] = ws[0] + ws[1] + ws[2] + ws[3];
}

__global__ __launch_bounds__(64) void scan_bscan_kernel(int* __restrict__ bsums, int NB) {
    int t = threadIdx.x;
    int v = (t < NB) ? bsums[t] : 0;
    int x = v;
    #pragma unroll
    for (int d = 1; d < 64; d <<= 1) {
        int y = __shfl_up(x, d);
        if (t >= d) x += y;
    }
    if (t < NB) bsums[t] = x - v;   // exclusive
}

__global__ __launch_bounds__(256) void scan_final_kernel(const int* __restrict__ counts,
                                                         const int* __restrict__ bsums,
                                                         int* __restrict__ offs, int N) {
    int t = threadIdx.x, lane = t & 63, w = t >> 6;
    int base = blockIdx.x * 1024 + t * 4;
    int v[4]; int s = 0;
    #pragma unroll
    for (int i = 0; i < 4; ++i) { int idx = base + i; v[i] = (idx < N) ? counts[idx] : 0; s += v[i]; }
    int x = s;
    #pragma unroll
    for (int d = 1; d < 64; d <<= 1) {
        int y = __shfl_up(x, d);
        if (lane >= d) x += y;
    }
    __shared__ int wtot[4];
    if (lane == 63) wtot[w] = x;
    __syncthreads();
    int wexc = 0;
    for (int i = 0; i < w; ++i) wexc += wtot[i];
    int run = (x - s) + wexc + bsums[blockIdx.x];
    #pragma unroll
    for (int i = 0; i < 4; ++i) {
        int idx = base + i;
        run += v[i];
        if (idx < N) offs[idx + 1] = run;
    }
    if (blockIdx.x == 0 && t == 0) offs[0] = 0;
}

__global__ __launch_bounds__(256) void scatter_kernel(
    const int* __restrict__ src, const int* __restrict__ dst,
    const int* __restrict__ offs, int* __restrict__ cursor,
    int* __restrict__ csr_src, int* __restrict__ csr_dst,
    int* __restrict__ csr_eid, int E) {
    int e = blockIdx.x * 256 + threadIdx.x;
    if (e >= E) return;
    int d = dst[e];
    int pos = offs[d] + atomicAdd(&cursor[d], 1);
    csr_src[pos] = src[e];
    csr_dst[pos] = d;
    csr_eid[pos] = e;
}

// canonical order: sort each dst-segment by eid (one wave per node, in-place, rank sort)
__global__ __launch_bounds__(256) void sort_segments_kernel(
    int* __restrict__ csr_src, int* __restrict__ csr_eid,
    const int* __restrict__ offs, int N)
{
    int t = threadIdx.x;
    int lane = t & 63;
    int node = blockIdx.x * 4 + (t >> 6);
    if (node >= N) return;
    int off = offs[node];
    int deg = offs[node + 1] - off;
    if (deg <= 1) return;
    if (deg <= 64) {
        int key = 0x7FFFFFFF, val = 0;
        if (lane < deg) { key = csr_eid[off + lane]; val = csr_src[off + lane]; }
        int rank = 0;
        #pragma unroll
        for (int i = 0; i < 64; ++i) {
            int ki = __shfl(key, i);
            if (ki < key) rank++;            // eids unique -> permutation
        }
        if (lane < deg) { csr_eid[off + rank] = key; csr_src[off + rank] = val; }
    } else if (lane == 0) {
        for (int a = 1; a < deg; ++a) {
            int k = csr_eid[off + a], v = csr_src[off + a];
            int b = a - 1;
            while (b >= 0 && csr_eid[off + b] > k) {
                csr_eid[off + b + 1] = csr_eid[off + b];
                csr_src[off + b + 1] = csr_src[off + b];
                b--;
            }
            csr_eid[off + b + 1] = k;
            csr_src[off + b + 1] = v;
        }
    }
}

// ---------------- per-layer kernels ----------------
#define ROWS_PER_WAVE 8
__global__ __launch_bounds__(256) void node_gemm_kernel(
    const float* __restrict__ hin,
    const float* __restrict__ Wl, const float* __restrict__ bl,
    const float* __restrict__ Wr, const float* __restrict__ br,
    float* __restrict__ xl, float* __restrict__ xr, int nrows)
{
    __shared__ float sWl[4096];
    __shared__ float sWr[4096];
    int t = threadIdx.x;
    {
        float4* dl = (float4*)sWl; const float4* sl = (const float4*)Wl;
        float4* dr = (float4*)sWr; const float4* sr = (const float4*)Wr;
        for (int i = t; i < 1024; i += 256) { dl[i] = sl[i]; dr[i] = sr[i]; }
    }
    __syncthreads();
    int lane = t & 63;
    int wave = t >> 6;
    int row0 = (blockIdx.x * 4 + wave) * ROWS_PER_WAVE;
    float xv[ROWS_PER_WAVE];
    #pragma unroll
    for (int r = 0; r < ROWS_PER_WAVE; ++r) {
        int row = row0 + r;
        xv[r] = (row < nrows) ? hin[(size_t)row * 64 + lane] : 0.f;
    }
    float b_l = bl[lane], b_r = br[lane];
    #pragma unroll
    for (int r = 0; r < ROWS_PER_WAVE; ++r) {
        int row = row0 + r;
        if (row >= nrows) break;
        // 4 independent partial chains per output (k in 4 chunks of 16) -> 8-way ILP
        float l0 = 0.f, l1 = 0.f, l2 = 0.f, l3 = 0.f;
        float r0 = 0.f, r1 = 0.f, r2 = 0.f, r3 = 0.f;
        #pragma unroll
        for (int kk = 0; kk < 16; ++kk) {
            float x0 = __shfl(xv[r], kk);
            float x1 = __shfl(xv[r], kk + 16);
            float x2 = __shfl(xv[r], kk + 32);
            float x3 = __shfl(xv[r], kk + 48);
            l0 += x0 * sWl[kk * 64 + lane];
            l1 += x1 * sWl[(kk + 16) * 64 + lane];
            l2 += x2 * sWl[(kk + 32) * 64 + lane];
            l3 += x3 * sWl[(kk + 48) * 64 + lane];
            r0 += x0 * sWr[kk * 64 + lane];
            r1 += x1 * sWr[(kk + 16) * 64 + lane];
            r2 += x2 * sWr[(kk + 32) * 64 + lane];
            r3 += x3 * sWr[(kk + 48) * 64 + lane];
        }
        xl[(size_t)row * 64 + lane] = b_l + ((l0 + l1) + (l2 + l3));
        xr[(size_t)row * 64 + lane] = b_r + ((r0 + r1) + (r2 + r3));
    }
}

// one thread per (CSR position, head): k-outer ef[16] accumulators for 16-way ILP
__global__ __launch_bounds__(256) void edge_score_kernel(
    const float* __restrict__ xl, const float* __restrict__ xr,
    const float* __restrict__ ea,
    const int* __restrict__ csr_src, const int* __restrict__ csr_dst,
    const int* __restrict__ csr_eid,
    const float* __restrict__ We, const float* __restrict__ att,
    float* __restrict__ score_csr, int E)
{
    __shared__ float sWe[1024];   // 16 x 64
    __shared__ float sAtt[64];    // 4 x 16
    int t = threadIdx.x;
    for (int i = t; i < 1024; i += 256) sWe[i] = We[i];
    if (t < 64) sAtt[t] = att[t];
    __syncthreads();
    int gid = blockIdx.x * 256 + t;
    int pos = gid >> 2, h = gid & 3;
    if (pos >= E) return;
    int s = csr_src[pos], d = csr_dst[pos], eid = csr_eid[pos];
    const float4* eap = (const float4*)(ea + (size_t)eid * 16);
    float4 a0 = eap[0], a1 = eap[1], a2 = eap[2], a3 = eap[3];
    float av[16] = {a0.x, a0.y, a0.z, a0.w, a1.x, a1.y, a1.z, a1.w,
                    a2.x, a2.y, a2.z, a2.w, a3.x, a3.y, a3.z, a3.w};
    const float4* xls = (const float4*)(xl + (size_t)s * 64 + h * 16);
    const float4* xrd = (const float4*)(xr + (size_t)d * 64 + h * 16);
    float4 vl0 = xls[0], vl1 = xls[1], vl2 = xls[2], vl3 = xls[3];
    float4 vr0 = xrd[0], vr1 = xrd[1], vr2 = xrd[2], vr3 = xrd[3];

    // ef[c] = sum_k av[k] * We[k][h*16+c] : 16 independent chains, fully unrolled
    float ef[16];
    #pragma unroll
    for (int c = 0; c < 16; ++c) ef[c] = 0.f;
    #pragma unroll
    for (int k = 0; k < 16; ++k) {
        float a = av[k];
        const float* wrow = &sWe[k * 64 + h * 16];
        #pragma unroll
        for (int c = 0; c < 16; ++c) ef[c] += a * wrow[c];
    }

    float lv[16] = {vl0.x, vl0.y, vl0.z, vl0.w, vl1.x, vl1.y, vl1.z, vl1.w,
                    vl2.x, vl2.y, vl2.z, vl2.w, vl3.x, vl3.y, vl3.z, vl3.w};
    float rv[16] = {vr0.x, vr0.y, vr0.z, vr0.w, vr1.x, vr1.y, vr1.z, vr1.w,
                    vr2.x, vr2.y, vr2.z, vr2.w, vr3.x, vr3.y, vr3.z, vr3.w};
    float sc0 = 0.f, sc1 = 0.f, sc2 = 0.f, sc3 = 0.f;
    #pragma unroll
    for (int c = 0; c < 16; c += 4) {
        float m0 = lv[c] + rv[c] + ef[c];
        float m1 = lv[c+1] + rv[c+1] + ef[c+1];
        float m2 = lv[c+2] + rv[c+2] + ef[c+2];
        float m3 = lv[c+3] + rv[c+3] + ef[c+3];
        m0 = (m0 >= 0.f) ? m0 : NEG_SLOPE * m0;
        m1 = (m1 >= 0.f) ? m1 : NEG_SLOPE * m1;
        m2 = (m2 >= 0.f) ? m2 : NEG_SLOPE * m2;
        m3 = (m3 >= 0.f) ? m3 : NEG_SLOPE * m3;
        sc0 += m0 * sAtt[h * 16 + c];
        sc1 += m1 * sAtt[h * 16 + c + 1];
        sc2 += m2 * sAtt[h * 16 + c + 2];
        sc3 += m3 * sAtt[h * 16 + c + 3];
    }
    score_csr[gid] = (sc0 + sc1) + (sc2 + sc3);
}

// one WAVE per node; lane = (edge-slot eg 0..3, channel-quad k 0..15, head = k>>2)
__global__ __launch_bounds__(256) void node_pass_kernel(
    const float* __restrict__ score_csr, const float* __restrict__ xl,
    const int* __restrict__ csr_src,
    const int* __restrict__ offs, const float* __restrict__ bias,
    float* __restrict__ hout, int N)
{
    int t = threadIdx.x;
    int lane = t & 63;
    int node = blockIdx.x * 4 + (t >> 6);
    if (node >= N) return;
    int eg = lane >> 4;          // edge slot
    int k  = lane & 15;          // channel quad; head = k>>2
    int h  = k >> 2;
    int off = offs[node];
    int deg = offs[node + 1] - off;

    if (deg == 0) {
        if (eg == 0) {
            float4 b = *(const float4*)(bias + k * 4);
            float4 o;
            o.x = fmaxf(b.x, 0.f); o.y = fmaxf(b.y, 0.f);
            o.z = fmaxf(b.z, 0.f); o.w = fmaxf(b.w, 0.f);
            *(float4*)(hout + (size_t)node * 64 + k * 4) = o;
        }
        return;
    }

    // pass 1: head max (exact, order-free)
    float mx = -FLT_MAX;
    for (int j0 = 0; j0 < deg; j0 += 4) {
        int j = j0 + eg;
        if (j < deg) {
            float sc = score_csr[(size_t)(off + j) * 4 + h];
            mx = fmaxf(mx, sc);
        }
    }
    mx = fmaxf(mx, __shfl_xor(mx, 16));
    mx = fmaxf(mx, __shfl_xor(mx, 32));

    // pass 2: 4 edges per iteration, float4 FMA payload
    float4 acc = {0.f, 0.f, 0.f, 0.f};
    float sSum = 0.f;
    for (int j0 = 0; j0 < deg; j0 += 4) {
        int j = j0 + eg;
        int jj = (j < deg) ? j : deg - 1;
        int pos = off + jj;
        int s = csr_src[pos];
        float sc = score_csr[(size_t)pos * 4 + h];
        float ex = (j < deg) ? __expf(sc - mx) : 0.f;
        float4 v = *(const float4*)(xl + (size_t)s * 64 + k * 4);
        acc.x += ex * v.x; acc.y += ex * v.y;
        acc.z += ex * v.z; acc.w += ex * v.w;
        sSum += ex;
    }

    // fixed-grouping butterfly reduce (deterministic)
    acc.x += __shfl_xor(acc.x, 16); acc.y += __shfl_xor(acc.y, 16);
    acc.z += __shfl_xor(acc.z, 16); acc.w += __shfl_xor(acc.w, 16);
    sSum  += __shfl_xor(sSum, 16);
    acc.x += __shfl_xor(acc.x, 32); acc.y += __shfl_xor(acc.y, 32);
    acc.z += __shfl_xor(acc.z, 32); acc.w += __shfl_xor(acc.w, 32);
    sSum  += __shfl_xor(sSum, 32);

    if (eg == 0) {
        float inv = 1.f / sSum;
        float4 b = *(const float4*)(bias + k * 4);
        float4 o;
        o.x = fmaxf(acc.x * inv + b.x, 0.f);
        o.y = fmaxf(acc.y * inv + b.y, 0.f);
        o.z = fmaxf(acc.z * inv + b.z, 0.f);
        o.w = fmaxf(acc.w * inv + b.w, 0.f);
        *(float4*)(hout + (size_t)node * 64 + k * 4) = o;
    }
}

extern "C" void kernel_launch(void* const* d_in, const int* in_sizes, int n_in,
                              void* d_out, int out_size, void* d_ws, size_t ws_size,
                              hipStream_t stream) {
    const float* x    = (const float*)d_in[0];
    const int*   eidx = (const int*)d_in[1];
    const float* ea   = (const float*)d_in[2];
    const float* Wl   = (const float*)d_in[3];
    const float* bl   = (const float*)d_in[4];
    const float* Wr   = (const float*)d_in[5];
    const float* br   = (const float*)d_in[6];
    const float* We   = (const float*)d_in[7];
    const float* att  = (const float*)d_in[8];
    const float* bias = (const float*)d_in[9];
    float* out = (float*)d_out;

    const int N = in_sizes[0] / 64;
    const int E = in_sizes[1] / 2;
    const int* src = eidx;
    const int* dst = eidx + E;

    float* ws = (float*)d_ws;
    float* xl      = ws;                               // N*64
    float* xr      = xl + (size_t)N * 64;              // N*64
    float* score   = xr + (size_t)N * 64;              // E*4 (CSR-indexed)
    float* h_tmp   = score + (size_t)E * 4;            // N*64
    int* counts    = (int*)(h_tmp + (size_t)N * 64);   // N
    int* cursor    = counts + N;                       // N
    int* offs      = cursor + N;                       // N+1
    int* csr_src   = offs + N + 1;                     // E
    int* csr_dst   = csr_src + E;                      // E
    int* csr_eid   = csr_dst + E;                      // E
    int* bsums     = csr_eid + E;                      // ~64

    dim3 blk(256);
    int g_n    = (N + 255) / 256;
    int g_e    = (E + 255) / 256;
    int g_eh   = (E * 4 + 255) / 256;
    int g_gemm = (N + 4 * ROWS_PER_WAVE - 1) / (4 * ROWS_PER_WAVE);
    int g_node = (N + 3) / 4;
    int NB     = (N + 1023) / 1024;   // 49 for N=50000 (<= 64)

    // CSR over dst, canonical eid order (edge_index is layer-invariant)
    zero_kernel<<<g_n, blk, 0, stream>>>(counts, cursor, N);
    count_kernel<<<g_e, blk, 0, stream>>>(dst, counts, E);
    scan_bsums_kernel<<<NB, blk, 0, stream>>>(counts, bsums, N);
    scan_bscan_kernel<<<1, 64, 0, stream>>>(bsums, NB);
    scan_final_kernel<<<NB, blk, 0, stream>>>(counts, bsums, offs, N);
    scatter_kernel<<<g_e, blk, 0, stream>>>(src, dst, offs, cursor,
                                            csr_src, csr_dst, csr_eid, E);
    sort_segments_kernel<<<g_node, blk, 0, stream>>>(csr_src, csr_eid, offs, N);

    const float* hin = x;
    for (int l = 0; l < 3; ++l) {
        float* hout = (l == 2) ? out : h_tmp;
        node_gemm_kernel<<<g_gemm, blk, 0, stream>>>(hin, Wl + (size_t)l * 4096, bl + l * 64,
                                                     Wr + (size_t)l * 4096, br + l * 64, xl, xr, N);
        edge_score_kernel<<<g_eh, blk, 0, stream>>>(xl, xr, ea, csr_src, csr_dst, csr_eid,
                                                    We + (size_t)l * 1024, att + l * 64,
                                                    score, E);
        node_pass_kernel<<<g_node, blk, 0, stream>>>(score, xl, csr_src, offs,
                                                     bias + l * 64, hout, N);
        hin = hout;
    }
}

// Round 14
// 512.456 us; speedup vs baseline: 1.8908x; 1.2432x over previous
//
#include <hip/hip_runtime.h>
#include <cfloat>

#define NEG_SLOPE 0.2f

// ---------------- CSR build ----------------
__global__ __launch_bounds__(256) void zero_kernel(int* __restrict__ counts,
                                                   int* __restrict__ cursor, int n) {
    int gid = blockIdx.x * 256 + threadIdx.x;
    if (gid < n) { counts[gid] = 0; cursor[gid] = 0; }
}

__global__ __launch_bounds__(256) void count_kernel(const int* __restrict__ dst,
                                                    int* __restrict__ counts, int E) {
    int e = blockIdx.x * 256 + threadIdx.x;
    if (e < E) atomicAdd(&counts[dst[e]], 1);
}

// ---- hierarchical scan: 1024 elements per block ----
__global__ __launch_bounds__(256) void scan_bsums_kernel(const int* __restrict__ counts,
                                                         int* __restrict__ bsums, int N) {
    int t = threadIdx.x;
    int base = blockIdx.x * 1024 + t * 4;
    int s = 0;
    #pragma unroll
    for (int i = 0; i < 4; ++i) { int idx = base + i; if (idx < N) s += counts[idx]; }
    #pragma unroll
    for (int d = 1; d < 64; d <<= 1) s += __shfl_xor(s, d);
    __shared__ int ws[4];
    if ((t & 63) == 0) ws[t >> 6] = s;
    __syncthreads();
    if (t == 0) bsums[blockIdx.x] = ws[0] + ws[1] + ws[2] + ws[3];
}

__global__ __launch_bounds__(64) void scan_bscan_kernel(int* __restrict__ bsums, int NB) {
    int t = threadIdx.x;
    int v = (t < NB) ? bsums[t] : 0;
    int x = v;
    #pragma unroll
    for (int d = 1; d < 64; d <<= 1) {
        int y = __shfl_up(x, d);
        if (t >= d) x += y;
    }
    if (t < NB) bsums[t] = x - v;   // exclusive
}

__global__ __launch_bounds__(256) void scan_final_kernel(const int* __restrict__ counts,
                                                         const int* __restrict__ bsums,
                                                         int* __restrict__ offs, int N) {
    int t = threadIdx.x, lane = t & 63, w = t >> 6;
    int base = blockIdx.x * 1024 + t * 4;
    int v[4]; int s = 0;
    #pragma unroll
    for (int i = 0; i < 4; ++i) { int idx = base + i; v[i] = (idx < N) ? counts[idx] : 0; s += v[i]; }
    int x = s;
    #pragma unroll
    for (int d = 1; d < 64; d <<= 1) {
        int y = __shfl_up(x, d);
        if (lane >= d) x += y;
    }
    __shared__ int wtot[4];
    if (lane == 63) wtot[w] = x;
    __syncthreads();
    int wexc = 0;
    for (int i = 0; i < w; ++i) wexc += wtot[i];
    int run = (x - s) + wexc + bsums[blockIdx.x];
    #pragma unroll
    for (int i = 0; i < 4; ++i) {
        int idx = base + i;
        run += v[i];
        if (idx < N) offs[idx + 1] = run;
    }
    if (blockIdx.x == 0 && t == 0) offs[0] = 0;
}

__global__ __launch_bounds__(256) void scatter_kernel(
    const int* __restrict__ src, const int* __restrict__ dst,
    const int* __restrict__ offs, int* __restrict__ cursor,
    int* __restrict__ csr_src, int* __restrict__ csr_dst,
    int* __restrict__ csr_eid, int E) {
    int e = blockIdx.x * 256 + threadIdx.x;
    if (e >= E) return;
    int d = dst[e];
    int pos = offs[d] + atomicAdd(&cursor[d], 1);
    csr_src[pos] = src[e];
    csr_dst[pos] = d;
    csr_eid[pos] = e;
}

// canonical order: sort each dst-segment by eid (one wave per node, in-place, rank sort)
__global__ __launch_bounds__(256) void sort_segments_kernel(
    int* __restrict__ csr_src, int* __restrict__ csr_eid,
    const int* __restrict__ offs, int N)
{
    int t = threadIdx.x;
    int lane = t & 63;
    int node = blockIdx.x * 4 + (t >> 6);
    if (node >= N) return;
    int off = offs[node];
    int deg = offs[node + 1] - off;
    if (deg <= 1) return;
    if (deg <= 64) {
        int key = 0x7FFFFFFF, val = 0;
        if (lane < deg) { key = csr_eid[off + lane]; val = csr_src[off + lane]; }
        int rank = 0;
        #pragma unroll
        for (int i = 0; i < 64; ++i) {
            int ki = __shfl(key, i);
            if (ki < key) rank++;            // eids unique -> permutation
        }
        if (lane < deg) { csr_eid[off + rank] = key; csr_src[off + rank] = val; }
    } else if (lane == 0) {
        for (int a = 1; a < deg; ++a) {
            int k = csr_eid[off + a], v = csr_src[off + a];
            int b = a - 1;
            while (b >= 0 && csr_eid[off + b] > k) {
                csr_eid[off + b + 1] = csr_eid[off + b];
                csr_src[off + b + 1] = csr_src[off + b];
                b--;
            }
            csr_eid[off + b + 1] = k;
            csr_src[off + b + 1] = v;
        }
    }
}

// ---------------- per-layer kernels ----------------
// v3: 64-row tile; lane=(row-slot rs, col-quad c4); x broadcast + W float4 from LDS.
// DS instrs per row: 48 (vs 192 in shfl version); 8 independent FMA chains.
#define XSTRIDE 68
__global__ __launch_bounds__(256) void node_gemm_kernel(
    const float* __restrict__ hin,
    const float* __restrict__ Wl, const float* __restrict__ bl,
    const float* __restrict__ Wr, const float* __restrict__ br,
    float* __restrict__ xl, float* __restrict__ xr, int nrows)
{
    __shared__ float sWl[4096];
    __shared__ float sWr[4096];
    __shared__ float sX[64 * XSTRIDE];
    int t = threadIdx.x;
    {
        float4* dl = (float4*)sWl; const float4* sl = (const float4*)Wl;
        float4* dr = (float4*)sWr; const float4* sr = (const float4*)Wr;
        for (int i = t; i < 1024; i += 256) { dl[i] = sl[i]; dr[i] = sr[i]; }
    }
    int row0 = blockIdx.x * 64;
    // stage 64 rows of hin into sX (padded stride 68 keeps float4 alignment + banks spread)
    for (int i = t; i < 1024; i += 256) {
        int rr = i >> 4;
        int cc = (i & 15) << 2;
        int row = row0 + rr;
        float4 v = make_float4(0.f, 0.f, 0.f, 0.f);
        if (row < nrows) v = *(const float4*)(hin + (size_t)row * 64 + cc);
        *(float4*)(&sX[rr * XSTRIDE + cc]) = v;
    }
    __syncthreads();

    int lane = t & 63;
    int w = t >> 6;
    int rs = lane >> 4;     // row slot 0..3
    int c4 = lane & 15;     // column quad 0..15
    float4 bl4 = *(const float4*)(bl + c4 * 4);
    float4 br4 = *(const float4*)(br + c4 * 4);

    #pragma unroll
    for (int g = 0; g < 4; ++g) {
        int rloc = w * 16 + g * 4 + rs;
        int row = row0 + rloc;
        float4 al = {0.f, 0.f, 0.f, 0.f};
        float4 ar = {0.f, 0.f, 0.f, 0.f};
        const float* xrow = &sX[rloc * XSTRIDE];
        #pragma unroll 4
        for (int k = 0; k < 64; ++k) {
            float xk = xrow[k];
            float4 wl4 = *(const float4*)(&sWl[k * 64 + c4 * 4]);
            float4 wr4 = *(const float4*)(&sWr[k * 64 + c4 * 4]);
            al.x += xk * wl4.x; al.y += xk * wl4.y;
            al.z += xk * wl4.z; al.w += xk * wl4.w;
            ar.x += xk * wr4.x; ar.y += xk * wr4.y;
            ar.z += xk * wr4.z; ar.w += xk * wr4.w;
        }
        if (row < nrows) {
            float4 ol, orr;
            ol.x = al.x + bl4.x; ol.y = al.y + bl4.y;
            ol.z = al.z + bl4.z; ol.w = al.w + bl4.w;
            orr.x = ar.x + br4.x; orr.y = ar.y + br4.y;
            orr.z = ar.z + br4.z; orr.w = ar.w + br4.w;
            *(float4*)(xl + (size_t)row * 64 + c4 * 4) = ol;
            *(float4*)(xr + (size_t)row * 64 + c4 * 4) = orr;
        }
    }
}

// one thread per (CSR position, head): k-outer ef[16] accumulators for 16-way ILP
__global__ __launch_bounds__(256) void edge_score_kernel(
    const float* __restrict__ xl, const float* __restrict__ xr,
    const float* __restrict__ ea,
    const int* __restrict__ csr_src, const int* __restrict__ csr_dst,
    const int* __restrict__ csr_eid,
    const float* __restrict__ We, const float* __restrict__ att,
    float* __restrict__ score_csr, int E)
{
    __shared__ float sWe[1024];   // 16 x 64
    __shared__ float sAtt[64];    // 4 x 16
    int t = threadIdx.x;
    for (int i = t; i < 1024; i += 256) sWe[i] = We[i];
    if (t < 64) sAtt[t] = att[t];
    __syncthreads();
    int gid = blockIdx.x * 256 + t;
    int pos = gid >> 2, h = gid & 3;
    if (pos >= E) return;
    int s = csr_src[pos], d = csr_dst[pos], eid = csr_eid[pos];
    const float4* eap = (const float4*)(ea + (size_t)eid * 16);
    float4 a0 = eap[0], a1 = eap[1], a2 = eap[2], a3 = eap[3];
    float av[16] = {a0.x, a0.y, a0.z, a0.w, a1.x, a1.y, a1.z, a1.w,
                    a2.x, a2.y, a2.z, a2.w, a3.x, a3.y, a3.z, a3.w};
    const float4* xls = (const float4*)(xl + (size_t)s * 64 + h * 16);
    const float4* xrd = (const float4*)(xr + (size_t)d * 64 + h * 16);
    float4 vl0 = xls[0], vl1 = xls[1], vl2 = xls[2], vl3 = xls[3];
    float4 vr0 = xrd[0], vr1 = xrd[1], vr2 = xrd[2], vr3 = xrd[3];

    float ef[16];
    #pragma unroll
    for (int c = 0; c < 16; ++c) ef[c] = 0.f;
    #pragma unroll
    for (int k = 0; k < 16; ++k) {
        float a = av[k];
        const float* wrow = &sWe[k * 64 + h * 16];
        #pragma unroll
        for (int c = 0; c < 16; ++c) ef[c] += a * wrow[c];
    }

    float lv[16] = {vl0.x, vl0.y, vl0.z, vl0.w, vl1.x, vl1.y, vl1.z, vl1.w,
                    vl2.x, vl2.y, vl2.z, vl2.w, vl3.x, vl3.y, vl3.z, vl3.w};
    float rv[16] = {vr0.x, vr0.y, vr0.z, vr0.w, vr1.x, vr1.y, vr1.z, vr1.w,
                    vr2.x, vr2.y, vr2.z, vr2.w, vr3.x, vr3.y, vr3.z, vr3.w};
    float sc0 = 0.f, sc1 = 0.f, sc2 = 0.f, sc3 = 0.f;
    #pragma unroll
    for (int c = 0; c < 16; c += 4) {
        float m0 = lv[c] + rv[c] + ef[c];
        float m1 = lv[c+1] + rv[c+1] + ef[c+1];
        float m2 = lv[c+2] + rv[c+2] + ef[c+2];
        float m3 = lv[c+3] + rv[c+3] + ef[c+3];
        m0 = (m0 >= 0.f) ? m0 : NEG_SLOPE * m0;
        m1 = (m1 >= 0.f) ? m1 : NEG_SLOPE * m1;
        m2 = (m2 >= 0.f) ? m2 : NEG_SLOPE * m2;
        m3 = (m3 >= 0.f) ? m3 : NEG_SLOPE * m3;
        sc0 += m0 * sAtt[h * 16 + c];
        sc1 += m1 * sAtt[h * 16 + c + 1];
        sc2 += m2 * sAtt[h * 16 + c + 2];
        sc3 += m3 * sAtt[h * 16 + c + 3];
    }
    score_csr[gid] = (sc0 + sc1) + (sc2 + sc3);
}

// one WAVE per node; lane = (edge-slot eg 0..3, channel-quad k 0..15, head = k>>2)
__global__ __launch_bounds__(256) void node_pass_kernel(
    const float* __restrict__ score_csr, const float* __restrict__ xl,
    const int* __restrict__ csr_src,
    const int* __restrict__ offs, const float* __restrict__ bias,
    float* __restrict__ hout, int N)
{
    int t = threadIdx.x;
    int lane = t & 63;
    int node = blockIdx.x * 4 + (t >> 6);
    if (node >= N) return;
    int eg = lane >> 4;          // edge slot
    int k  = lane & 15;          // channel quad; head = k>>2
    int h  = k >> 2;
    int off = offs[node];
    int deg = offs[node + 1] - off;

    if (deg == 0) {
        if (eg == 0) {
            float4 b = *(const float4*)(bias + k * 4);
            float4 o;
            o.x = fmaxf(b.x, 0.f); o.y = fmaxf(b.y, 0.f);
            o.z = fmaxf(b.z, 0.f); o.w = fmaxf(b.w, 0.f);
            *(float4*)(hout + (size_t)node * 64 + k * 4) = o;
        }
        return;
    }

    // pass 1: head max (exact, order-free)
    float mx = -FLT_MAX;
    for (int j0 = 0; j0 < deg; j0 += 4) {
        int j = j0 + eg;
        if (j < deg) {
            float sc = score_csr[(size_t)(off + j) * 4 + h];
            mx = fmaxf(mx, sc);
        }
    }
    mx = fmaxf(mx, __shfl_xor(mx, 16));
    mx = fmaxf(mx, __shfl_xor(mx, 32));

    // pass 2: 4 edges per iteration, float4 FMA payload
    float4 acc = {0.f, 0.f, 0.f, 0.f};
    float sSum = 0.f;
    for (int j0 = 0; j0 < deg; j0 += 4) {
        int j = j0 + eg;
        int jj = (j < deg) ? j : deg - 1;
        int pos = off + jj;
        int s = csr_src[pos];
        float sc = score_csr[(size_t)pos * 4 + h];
        float ex = (j < deg) ? __expf(sc - mx) : 0.f;
        float4 v = *(const float4*)(xl + (size_t)s * 64 + k * 4);
        acc.x += ex * v.x; acc.y += ex * v.y;
        acc.z += ex * v.z; acc.w += ex * v.w;
        sSum += ex;
    }

    // fixed-grouping butterfly reduce (deterministic)
    acc.x += __shfl_xor(acc.x, 16); acc.y += __shfl_xor(acc.y, 16);
    acc.z += __shfl_xor(acc.z, 16); acc.w += __shfl_xor(acc.w, 16);
    sSum  += __shfl_xor(sSum, 16);
    acc.x += __shfl_xor(acc.x, 32); acc.y += __shfl_xor(acc.y, 32);
    acc.z += __shfl_xor(acc.z, 32); acc.w += __shfl_xor(acc.w, 32);
    sSum  += __shfl_xor(sSum, 32);

    if (eg == 0) {
        float inv = 1.f / sSum;
        float4 b = *(const float4*)(bias + k * 4);
        float4 o;
        o.x = fmaxf(acc.x * inv + b.x, 0.f);
        o.y = fmaxf(acc.y * inv + b.y, 0.f);
        o.z = fmaxf(acc.z * inv + b.z, 0.f);
        o.w = fmaxf(acc.w * inv + b.w, 0.f);
        *(float4*)(hout + (size_t)node * 64 + k * 4) = o;
    }
}

extern "C" void kernel_launch(void* const* d_in, const int* in_sizes, int n_in,
                              void* d_out, int out_size, void* d_ws, size_t ws_size,
                              hipStream_t stream) {
    const float* x    = (const float*)d_in[0];
    const int*   eidx = (const int*)d_in[1];
    const float* ea   = (const float*)d_in[2];
    const float* Wl   = (const float*)d_in[3];
    const float* bl   = (const float*)d_in[4];
    const float* Wr   = (const float*)d_in[5];
    const float* br   = (const float*)d_in[6];
    const float* We   = (const float*)d_in[7];
    const float* att  = (const float*)d_in[8];
    const float* bias = (const float*)d_in[9];
    float* out = (float*)d_out;

    const int N = in_sizes[0] / 64;
    const int E = in_sizes[1] / 2;
    const int* src = eidx;
    const int* dst = eidx + E;

    float* ws = (float*)d_ws;
    float* xl      = ws;                               // N*64
    float* xr      = xl + (size_t)N * 64;              // N*64
    float* score   = xr + (size_t)N * 64;              // E*4 (CSR-indexed)
    float* h_tmp   = score + (size_t)E * 4;            // N*64
    int* counts    = (int*)(h_tmp + (size_t)N * 64);   // N
    int* cursor    = counts + N;                       // N
    int* offs      = cursor + N;                       // N+1
    int* csr_src   = offs + N + 1;                     // E
    int* csr_dst   = csr_src + E;                      // E
    int* csr_eid   = csr_dst + E;                      // E
    int* bsums     = csr_eid + E;                      // ~64

    dim3 blk(256);
    int g_n    = (N + 255) / 256;
    int g_e    = (E + 255) / 256;
    int g_eh   = (E * 4 + 255) / 256;
    int g_gemm = (N + 63) / 64;
    int g_node = (N + 3) / 4;
    int NB     = (N + 1023) / 1024;   // 49 for N=50000 (<= 64)

    // CSR over dst, canonical eid order (edge_index is layer-invariant)
    zero_kernel<<<g_n, blk, 0, stream>>>(counts, cursor, N);
    count_kernel<<<g_e, blk, 0, stream>>>(dst, counts, E);
    scan_bsums_kernel<<<NB, blk, 0, stream>>>(counts, bsums, N);
    scan_bscan_kernel<<<1, 64, 0, stream>>>(bsums, NB);
    scan_final_kernel<<<NB, blk, 0, stream>>>(counts, bsums, offs, N);
    scatter_kernel<<<g_e, blk, 0, stream>>>(src, dst, offs, cursor,
                                            csr_src, csr_dst, csr_eid, E);
    sort_segments_kernel<<<g_node, blk, 0, stream>>>(csr_src, csr_eid, offs, N);

    const float* hin = x;
    for (int l = 0; l < 3; ++l) {
        float* hout = (l == 2) ? out : h_tmp;
        node_gemm_kernel<<<g_gemm, blk, 0, stream>>>(hin, Wl + (size_t)l * 4096, bl + l * 64,
                                                     Wr + (size_t)l * 4096, br + l * 64, xl, xr, N);
        edge_score_kernel<<<g_eh, blk, 0, stream>>>(xl, xr, ea, csr_src, csr_dst, csr_eid,
                                                    We + (size_t)l * 1024, att + l * 64,
                                                    score, E);
        node_pass_kernel<<<g_node, blk, 0, stream>>>(score, xl, csr_src, offs,
                                                     bias + l * 64, hout, N);
        hin = hout;
    }
}